// Round 10
// baseline (2538.482 us; speedup 1.0000x reference)
//
#include <hip/hip_runtime.h>
#include <math.h>

#define B_LEN 1024
#define T_LEN 256
#define HST 36   // hid_sh leading stride keeps float4 access conflict-light
#define TS 20    // dxT/ypT row stride (17 used + 3 pad): banks 20*r%32 distinct

__device__ __forceinline__ float fast_rcp(float x) { return __builtin_amdgcn_rcpf(x); }
__device__ __forceinline__ float fast_rsq(float x) { return __builtin_amdgcn_rsqf(x); }
__device__ __forceinline__ float lane_bcast(float v, int l) {
    return __int_as_float(__builtin_amdgcn_readlane(__float_as_int(v), l));
}
__device__ __forceinline__ float fast_tanh(float x) {
    float e = __expf(2.0f * x);
    return 1.0f - 2.0f * fast_rcp(e + 1.0f);
}
__device__ __forceinline__ float softplus_f(float x) {
    return (x > 20.0f) ? x : log1pf(expf(x));
}
// weighted 17-dot: 0.0625*sum(all 17) + (2-0.0625)*center  (Wc0=2, rest 1/16)
__device__ __forceinline__ float wdot17(const float* __restrict__ a,
                                        const float* __restrict__ b) {
    float full = 0.0f;
    #pragma unroll
    for (int c = 0; c < 4; ++c) {
        const float4 av = *(const float4*)&a[c * 4];
        const float4 bv = *(const float4*)&b[c * 4];
        full += av.x * bv.x + av.y * bv.y + av.z * bv.z + av.w * bv.w;
    }
    full += a[16] * b[16];
    return 0.0625f * full + 1.9375f * a[0] * b[0];
}

// FOUR WAVES PER BATCH (256-thread blocks, grid=1024). R9's de-phasing was
// neutral -> the 41% dual-idle at 2 waves/SIMD is intrinsic chain latency.
// Only remaining mechanism: MORE co-resident streams. 1024 blocks x 4 waves
// = 4 blocks/CU x 16 waves/CU = 4 waves/SIMD (VGPR<=128 permits it; R4
// measured 1.61x for 1->2/SIMD). ALL 4 barriers and phase bodies preserved
// from the verified 750us R8 kernel -- only the wave predicates change:
//   A[w0 chol8] B[rows 4w..4w+3/wave, 16 on w3; L1+L2 same-wave per row]
//   C[w0 dxT, w1 ypT] D[w0 Ppred | w2 Pxy | w3 Sy+cofactor] E[w0 main, w1 qe]
// Hazard audit: dxT/ypT->w2,w3 fenced b3; Pp->w1, Pxy/Si->w0 fenced b4;
// cross-step WAR via the b4->b1 rendezvous. Idle waves cede SIMD slots to
// the 3 other co-resident blocks.
__global__ __launch_bounds__(256, 4)
void ukf_kernel(const float* __restrict__ X0, const float* __restrict__ U,
                const float* __restrict__ Y,  const float* __restrict__ W1,
                const float* __restrict__ B1, const float* __restrict__ W2,
                const float* __restrict__ B2, const float* __restrict__ HM,
                const float* __restrict__ LQ, const float* __restrict__ LR,
                const float* __restrict__ LP0, float* __restrict__ out)
{
    const int tid  = threadIdx.x;
    const int wid  = tid >> 6;        // 0..3
    const int lane = tid & 63;
    const int b    = blockIdx.x;
    const int k8   = lane & 7;        // column / j8
    const int g8   = lane >> 3;       // replica group / i8
    const int i8   = g8;
    const int j8   = k8;
    const int h32  = lane & 31;
    const int p2   = lane >> 5;       // half-wave (L1 row parity)
    const int m4   = lane & 3;
    const int sy   = lane >> 2;

    __shared__ __align__(16) float u_sh[T_LEN * 2];
    __shared__ __align__(16) float y_sh[T_LEN * 4];
    __shared__ __align__(16) float pts_sh[17 * 8];
    __shared__ __align__(16) float hid_sh[17 * HST];
    __shared__ __align__(16) float pf_sh[17 * 8];
    __shared__ __align__(16) float dxT_sh[8 * TS];   // dxT[d][s]
    __shared__ __align__(16) float ypT_sh[4 * TS];   // ypT[m][s]
    __shared__ __align__(16) float xp_sh[8];
    __shared__ __align__(16) float ypred_sh[4];
    __shared__ __align__(16) float Sy_sh[16];
    __shared__ __align__(16) float Si_sh[16];
    __shared__ __align__(16) float Pxy_sh[32];
    __shared__ __align__(16) float Pp_sh[64];

    // ---- one-time staging (256 threads) ----
    for (int k = tid; k < T_LEN * 2; k += 256) u_sh[k] = U[(size_t)b * (T_LEN * 2) + k];
    for (int k = tid; k < T_LEN * 4; k += 256) y_sh[k] = Y[(size_t)b * (T_LEN * 4) + k];

    float w1r[10];
    #pragma unroll
    for (int d = 0; d < 10; ++d) w1r[d] = W1[d * 32 + h32];
    const float b1r = B1[h32];
    float w2r[32];
    #pragma unroll
    for (int h = 0; h < 32; ++h) w2r[h] = W2[h * 8 + k8];
    const float b2r = B2[k8];
    float hmr[8];                              // wave1 only (ypT)
    #pragma unroll
    for (int d = 0; d < 8; ++d) hmr[d] = HM[m4 * 8 + d];

    const float qdiag = softplus_f(LQ[i8]);    // w0 Ppred
    const float rdiag = softplus_f(LR[m4]);    // w3 Sy

    const size_t Xbase = (size_t)b * T_LEN * 8;
    const size_t Pbase = (size_t)B_LEN * T_LEN * 8  + (size_t)b * T_LEN * 64;
    const size_t qbase = (size_t)B_LEN * T_LEN * 72 + (size_t)b * T_LEN;
    const size_t rbase = (size_t)B_LEN * T_LEN * 73 + (size_t)b * T_LEN;

    // ---- persistent register state (w0): x replicated, P column k8 ----
    float xn[8], Pc[8];
    {
        const float4 xa = *(const float4*)&X0[b * 8];
        const float4 xb = *(const float4*)&X0[b * 8 + 4];
        xn[0] = xa.x; xn[1] = xa.y; xn[2] = xa.z; xn[3] = xa.w;
        xn[4] = xb.x; xn[5] = xb.y; xn[6] = xb.z; xn[7] = xb.w;
        const float p0k = softplus_f(LP0[k8]);
        #pragma unroll
        for (int i = 0; i < 8; ++i) Pc[i] = (i == k8) ? p0k : 0.0f;
    }
    if (wid == 0) {
        out[Pbase + lane] = Pc[g8];                  // coalesced 64-lane P store
        if (lane == 0) {
            *(float4*)&out[Xbase]     = make_float4(xn[0], xn[1], xn[2], xn[3]);
            *(float4*)&out[Xbase + 4] = make_float4(xn[4], xn[5], xn[6], xn[7]);
            out[qbase] = 0.0f; out[rbase] = 0.0f;
        }
    }

    for (int t = 1; t < T_LEN; ++t) {
        // ===== Phase A [w0]: branchless column-chol8 of 8P+jitter -> pts =====
        if (wid == 0) {
            float a[8];
            #pragma unroll
            for (int i = 0; i < 8; ++i) a[i] = 8.0f * Pc[i] + ((i == k8) ? 1e-4f : 0.0f);
            #pragma unroll
            for (int j = 0; j < 8; ++j) {
                const float dj = lane_bcast(a[j], j);
                const float rv = fast_rsq(dj);
                const float sc = (k8 == j) ? rv : 1.0f;
                const float tc = (k8 > j) ? a[j] * (rv * rv) : 0.0f;
                float u[8];
                #pragma unroll
                for (int i = j + 1; i < 8; ++i) u[i] = lane_bcast(a[i], j);
                #pragma unroll
                for (int i = j + 1; i < 8; ++i) a[i] = sc * a[i] - tc * u[i];
                a[j] = (k8 == j) ? dj * rv : a[j];
            }
            float Lc[8];
            #pragma unroll
            for (int i = 0; i < 8; ++i) Lc[i] = (i >= k8) ? a[i] : 0.0f;
            if (g8 == 0) {
                *(float4*)&pts_sh[(1 + k8) * 8] =
                    make_float4(xn[0] + Lc[0], xn[1] + Lc[1], xn[2] + Lc[2], xn[3] + Lc[3]);
                *(float4*)&pts_sh[(1 + k8) * 8 + 4] =
                    make_float4(xn[4] + Lc[4], xn[5] + Lc[5], xn[6] + Lc[6], xn[7] + Lc[7]);
            } else if (g8 == 1) {
                *(float4*)&pts_sh[(9 + k8) * 8] =
                    make_float4(xn[0] - Lc[0], xn[1] - Lc[1], xn[2] - Lc[2], xn[3] - Lc[3]);
                *(float4*)&pts_sh[(9 + k8) * 8 + 4] =
                    make_float4(xn[4] - Lc[4], xn[5] - Lc[5], xn[6] - Lc[6], xn[7] - Lc[7]);
            } else if (g8 == 2 && k8 == 0) {
                *(float4*)&pts_sh[0] = make_float4(xn[0], xn[1], xn[2], xn[3]);
                *(float4*)&pts_sh[4] = make_float4(xn[4], xn[5], xn[6], xn[7]);
            }
        }
        __syncthreads();   // b1: pts ready

        // ===== Phase B [all 4]: L1+L2 on rows 4*wid..4*wid+3 (w3: +row 16) ====
        {
            const float u0 = u_sh[(t - 1) * 2 + 0];
            const float u1 = u_sh[(t - 1) * 2 + 1];
            const float ub = b1r + u0 * w1r[8] + u1 * w1r[9];
            #pragma unroll
            for (int p = 0; p < 2; ++p) {
                const int s = 4 * wid + 2 * p + p2;           // rows 4w..4w+3
                const float4 pa = *(const float4*)&pts_sh[s * 8];
                const float4 pb = *(const float4*)&pts_sh[s * 8 + 4];
                float acc = ub
                    + pa.x * w1r[0] + pa.y * w1r[1] + pa.z * w1r[2] + pa.w * w1r[3]
                    + pb.x * w1r[4] + pb.y * w1r[5] + pb.z * w1r[6] + pb.w * w1r[7];
                hid_sh[s * HST + h32] = fast_tanh(acc);
            }
            if (wid == 3 && p2 == 0) {                        // row 16
                const float4 pa = *(const float4*)&pts_sh[16 * 8];
                const float4 pb = *(const float4*)&pts_sh[16 * 8 + 4];
                float acc = ub
                    + pa.x * w1r[0] + pa.y * w1r[1] + pa.z * w1r[2] + pa.w * w1r[3]
                    + pb.x * w1r[4] + pb.y * w1r[5] + pb.z * w1r[6] + pb.w * w1r[7];
                hid_sh[16 * HST + h32] = fast_tanh(acc);
            }
            // L2 on own-wave rows (same-wave DS in-order: no barrier)
            if (g8 < 4) {
                const int srow = 4 * wid + g8;
                float acc = b2r;
                #pragma unroll
                for (int h = 0; h < 32; h += 4) {
                    const float4 hv = *(const float4*)&hid_sh[srow * HST + h];
                    acc += hv.x * w2r[h] + hv.y * w2r[h + 1] + hv.z * w2r[h + 2] + hv.w * w2r[h + 3];
                }
                pf_sh[srow * 8 + k8] = pts_sh[srow * 8 + k8] + acc;
            } else if (wid == 3 && g8 == 4) {                 // row 16, col k8
                float a16 = b2r;
                #pragma unroll
                for (int h = 0; h < 32; h += 4) {
                    const float4 hv = *(const float4*)&hid_sh[16 * HST + h];
                    a16 += hv.x * w2r[h] + hv.y * w2r[h + 1] + hv.z * w2r[h + 2] + hv.w * w2r[h + 3];
                }
                pf_sh[16 * 8 + k8] = pts_sh[16 * 8 + k8] + a16;
            }
        }
        __syncthreads();   // b2: pf ready

        // ===== Phase C [w0]: x_pred + dxT ; [w1]: y_pts + ypred + ypT =========
        if (wid == 0) {
            const float v0   = pf_sh[i8 * 8 + j8];
            const float v1   = pf_sh[(8 + i8) * 8 + j8];
            const float pf16 = (i8 == 0) ? pf_sh[16 * 8 + j8] : 0.0f;
            float part = ((i8 == 0) ? pf16 : v0) + v1;        // s=16 replaces s=0
            part += __shfl_xor(part, 8);
            part += __shfl_xor(part, 16);
            part += __shfl_xor(part, 32);
            const float xp = part * 0.0625f;
            if (i8 == 0) xp_sh[j8] = xp;
            dxT_sh[j8 * TS + i8]       = v0 - xp;             // dxT[d][s]
            dxT_sh[j8 * TS + 8 + i8]   = v1 - xp;
            if (i8 == 0) dxT_sh[j8 * TS + 16] = pf16 - xp;
        } else if (wid == 1) {
            float yv0, yv16 = 0.0f;
            {
                const float4 pa = *(const float4*)&pf_sh[sy * 8];
                const float4 pb = *(const float4*)&pf_sh[sy * 8 + 4];
                yv0 = pa.x * hmr[0] + pa.y * hmr[1] + pa.z * hmr[2] + pa.w * hmr[3]
                    + pb.x * hmr[4] + pb.y * hmr[5] + pb.z * hmr[6] + pb.w * hmr[7];
            }
            if (sy == 0) {
                const float4 pa = *(const float4*)&pf_sh[16 * 8];
                const float4 pb = *(const float4*)&pf_sh[16 * 8 + 4];
                yv16 = pa.x * hmr[0] + pa.y * hmr[1] + pa.z * hmr[2] + pa.w * hmr[3]
                     + pb.x * hmr[4] + pb.y * hmr[5] + pb.z * hmr[6] + pb.w * hmr[7];
            }
            float py = (sy == 0) ? yv16 : yv0;
            py += __shfl_xor(py, 4);
            py += __shfl_xor(py, 8);
            py += __shfl_xor(py, 16);
            py += __shfl_xor(py, 32);
            const float ypred = py * 0.0625f;
            if (lane < 4) ypred_sh[lane] = ypred;
            ypT_sh[m4 * TS + sy] = yv0 - ypred;               // ypT[m][s]
            if (sy == 0) ypT_sh[m4 * TS + 16] = yv16 - ypred;
        }
        __syncthreads();   // b3: dxT, ypT, xp, ypred ready

        // ===== Phase D: [w0] Ppred ; [w2] Pxy ; [w3] Sy -> cofactor Si ========
        float Ppc[8];
        if (wid == 0) {
            const float Ppred = wdot17(&dxT_sh[i8 * TS], &dxT_sh[j8 * TS])
                              + ((i8 == j8) ? (qdiag + 1e-4f) : 0.0f);
            Pp_sh[lane] = Ppred;
            // Pp exactly symmetric -> column k8 == row k8 (contiguous):
            // 2x ds_read_b128, 2-way bank alias (free), in-wave ordering.
            const float4 pa = *(const float4*)&Pp_sh[k8 * 8];
            const float4 pb = *(const float4*)&Pp_sh[k8 * 8 + 4];
            Ppc[0]=pa.x; Ppc[1]=pa.y; Ppc[2]=pa.z; Ppc[3]=pa.w;
            Ppc[4]=pb.x; Ppc[5]=pb.y; Ppc[6]=pb.z; Ppc[7]=pb.w;
        } else if (wid == 2) {
            // Pxy(ii=sy, mm=m4) on lanes<32; dxT/ypT reads fenced by b3
            if (lane < 32)
                Pxy_sh[lane] = wdot17(&dxT_sh[sy * TS], &ypT_sh[m4 * TS]);
        } else if (wid == 3) {
            // Sy on lanes<16 (sy=row 0..3, m4=col); then cofactor inverse
            if (lane < 16)
                Sy_sh[lane] = wdot17(&ypT_sh[sy * TS], &ypT_sh[m4 * TS])
                            + ((sy == m4) ? rdiag : 0.0f);
            // parallel cofactor inverse (R7-verified); Sy_sh read in-wave
            float cof;
            {
                const int i4 = sy & 3;
                const int j4 = m4;
                const int r0 = (i4 == 0) ? 1 : 0;
                const int r1 = (i4 <= 1) ? 2 : 1;
                const int rr = (i4 <= 2) ? 3 : 2;
                const int c0 = (j4 == 0) ? 1 : 0;
                const int c1 = (j4 <= 1) ? 2 : 1;
                const int cc = (j4 <= 2) ? 3 : 2;
                const float m00 = Sy_sh[r0 * 4 + c0], m01 = Sy_sh[r0 * 4 + c1], m02 = Sy_sh[r0 * 4 + cc];
                const float m10 = Sy_sh[r1 * 4 + c0], m11 = Sy_sh[r1 * 4 + c1], m12 = Sy_sh[r1 * 4 + cc];
                const float m20 = Sy_sh[rr * 4 + c0], m21 = Sy_sh[rr * 4 + c1], m22 = Sy_sh[rr * 4 + cc];
                const float d3 = m00 * (m11 * m22 - m12 * m21)
                               - m01 * (m10 * m22 - m12 * m20)
                               + m02 * (m10 * m21 - m11 * m20);
                cof = (((i4 + j4) & 1) ? -d3 : d3);
            }
            const float c0b = lane_bcast(cof, 0);
            const float c1b = lane_bcast(cof, 1);
            const float c2b = lane_bcast(cof, 2);
            const float c3b = lane_bcast(cof, 3);
            const float4 sy0 = *(const float4*)&Sy_sh[0];
            const float det = sy0.x * c0b + sy0.y * c1b + sy0.z * c2b + sy0.w * c3b;
            if (lane == 0) out[rbase + t] = 0.5f * __logf(det);
            const float rdet = fast_rcp(det);
            if (lane < 16) Si_sh[lane] = cof * rdet;
        }
        __syncthreads();   // b4: Pp / Si / Pxy ready

        // ===== Phase E: [w0] kk -> P_new(symmetric form), x_new ; [w1] qe =====
        if (wid == 0) {
            float Si[16];
            {
                const float4 a0 = *(const float4*)&Si_sh[0];
                const float4 a1 = *(const float4*)&Si_sh[4];
                const float4 a2 = *(const float4*)&Si_sh[8];
                const float4 a3 = *(const float4*)&Si_sh[12];
                Si[0]=a0.x;  Si[1]=a0.y;  Si[2]=a0.z;  Si[3]=a0.w;
                Si[4]=a1.x;  Si[5]=a1.y;  Si[6]=a1.z;  Si[7]=a1.w;
                Si[8]=a2.x;  Si[9]=a2.y;  Si[10]=a2.z; Si[11]=a2.w;
                Si[12]=a3.x; Si[13]=a3.y; Si[14]=a3.z; Si[15]=a3.w;
            }
            const float4 pr = *(const float4*)&Pxy_sh[k8 * 4];     // Pxy row k8
            float kk[4];
            #pragma unroll
            for (int aa = 0; aa < 4; ++aa)
                kk[aa] = pr.x * Si[0 * 4 + aa] + pr.y * Si[1 * 4 + aa]
                       + pr.z * Si[2 * 4 + aa] + pr.w * Si[3 * 4 + aa];
            // all 8 Pxy rows (broadcast LDS reads, compile-time indexed regs)
            float Pr[32];
            {
                const float4 q0 = *(const float4*)&Pxy_sh[0];
                const float4 q1 = *(const float4*)&Pxy_sh[4];
                const float4 q2 = *(const float4*)&Pxy_sh[8];
                const float4 q3 = *(const float4*)&Pxy_sh[12];
                const float4 q4 = *(const float4*)&Pxy_sh[16];
                const float4 q5 = *(const float4*)&Pxy_sh[20];
                const float4 q6 = *(const float4*)&Pxy_sh[24];
                const float4 q7 = *(const float4*)&Pxy_sh[28];
                Pr[0]=q0.x;  Pr[1]=q0.y;  Pr[2]=q0.z;  Pr[3]=q0.w;
                Pr[4]=q1.x;  Pr[5]=q1.y;  Pr[6]=q1.z;  Pr[7]=q1.w;
                Pr[8]=q2.x;  Pr[9]=q2.y;  Pr[10]=q2.z; Pr[11]=q2.w;
                Pr[12]=q3.x; Pr[13]=q3.y; Pr[14]=q3.z; Pr[15]=q3.w;
                Pr[16]=q4.x; Pr[17]=q4.y; Pr[18]=q4.z; Pr[19]=q4.w;
                Pr[20]=q5.x; Pr[21]=q5.y; Pr[22]=q5.z; Pr[23]=q5.w;
                Pr[24]=q6.x; Pr[25]=q6.y; Pr[26]=q6.z; Pr[27]=q6.w;
                Pr[28]=q7.x; Pr[29]=q7.y; Pr[30]=q7.z; Pr[31]=q7.w;
            }
            // P_new column k8: Pc[i] = Ppc[i] - dot(kk, Pxy row i)  (+ jitter)
            #pragma unroll
            for (int i = 0; i < 8; ++i) {
                const float m = kk[0] * Pr[i * 4 + 0] + kk[1] * Pr[i * 4 + 1]
                              + kk[2] * Pr[i * 4 + 2] + kk[3] * Pr[i * 4 + 3];
                Pc[i] = Ppc[i] - m + ((i == k8) ? 1e-4f : 0.0f);
            }
            // x_new: own row k8 then broadcast (lane r<8 has k8==r)
            const float4 yt = *(const float4*)&y_sh[t * 4];
            const float4 yp = *(const float4*)&ypred_sh[0];
            const float in0 = yt.x - yp.x, in1 = yt.y - yp.y;
            const float in2 = yt.z - yp.z, in3 = yt.w - yp.w;
            const float xo = xp_sh[k8]
                           + kk[0] * in0 + kk[1] * in1 + kk[2] * in2 + kk[3] * in3;
            #pragma unroll
            for (int i = 0; i < 8; ++i) xn[i] = lane_bcast(xo, i);
            // stores: coalesced 64-lane P store (lane (g8,k8) owns P[g8][k8])
            out[Pbase + (size_t)t * 64 + lane] = Pc[g8];
            if (lane == 0) {
                *(float4*)&out[Xbase + (size_t)t * 8]     = make_float4(xn[0], xn[1], xn[2], xn[3]);
                *(float4*)&out[Xbase + (size_t)t * 8 + 4] = make_float4(xn[4], xn[5], xn[6], xn[7]);
            }
        } else if (wid == 1) {
            // qe = 0.5 slogdet(P_pred): branchless column LDL; aq = Pp row k8
            float aq[8];
            {
                const float4 pa = *(const float4*)&Pp_sh[k8 * 8];
                const float4 pb = *(const float4*)&Pp_sh[k8 * 8 + 4];
                aq[0]=pa.x; aq[1]=pa.y; aq[2]=pa.z; aq[3]=pa.w;
                aq[4]=pb.x; aq[5]=pb.y; aq[6]=pb.z; aq[7]=pb.w;
            }
            float qe = 0.0f;
            #pragma unroll
            for (int j = 0; j < 8; ++j) {
                const float dj  = lane_bcast(aq[j], j);
                qe += __logf(dj);
                const float rv2 = fast_rcp(dj);
                const float tq  = (k8 > j) ? aq[j] * rv2 : 0.0f;
                float u[8];
                #pragma unroll
                for (int i = j + 1; i < 8; ++i) u[i] = lane_bcast(aq[i], j);
                #pragma unroll
                for (int i = j + 1; i < 8; ++i) aq[i] = fmaf(-tq, u[i], aq[i]);
            }
            if (lane == 0) out[qbase + t] = 0.5f * qe;
        }
        // no trailing barrier: next-step hazards are covered by b1..b4 ordering
    }
}

extern "C" void kernel_launch(void* const* d_in, const int* in_sizes, int n_in,
                              void* d_out, int out_size, void* d_ws, size_t ws_size,
                              hipStream_t stream) {
    (void)in_sizes; (void)n_in; (void)out_size; (void)d_ws; (void)ws_size;
    const float* X0 = (const float*)d_in[0];
    const float* U  = (const float*)d_in[1];
    const float* Y  = (const float*)d_in[2];
    const float* W1 = (const float*)d_in[3];
    const float* B1 = (const float*)d_in[4];
    const float* W2 = (const float*)d_in[5];
    const float* B2 = (const float*)d_in[6];
    const float* HM = (const float*)d_in[7];
    const float* LQ = (const float*)d_in[8];
    const float* LR = (const float*)d_in[9];
    const float* LP0 = (const float*)d_in[10];
    float* out = (float*)d_out;
    ukf_kernel<<<dim3(B_LEN), dim3(256), 0, stream>>>(X0, U, Y, W1, B1, W2, B2,
                                                      HM, LQ, LR, LP0, out);
}

// Round 11
// 1427.665 us; speedup vs baseline: 1.7781x; 1.7781x over previous
//
#include <hip/hip_runtime.h>
#include <math.h>

#define B_LEN 1024
#define T_LEN 256
#define HST 36   // hid_sh leading stride keeps float4 access conflict-light
#define TS 20    // dxT/ypT row stride (17 used + 3 pad): banks 20*r%32 distinct

__device__ __forceinline__ float fast_rcp(float x) { return __builtin_amdgcn_rcpf(x); }
__device__ __forceinline__ float fast_rsq(float x) { return __builtin_amdgcn_rsqf(x); }
__device__ __forceinline__ float lane_bcast(float v, int l) {
    return __int_as_float(__builtin_amdgcn_readlane(__float_as_int(v), l));
}
__device__ __forceinline__ float fast_tanh(float x) {
    float e = __expf(2.0f * x);
    return 1.0f - 2.0f * fast_rcp(e + 1.0f);
}
__device__ __forceinline__ float softplus_f(float x) {
    return (x > 20.0f) ? x : log1pf(expf(x));
}
// weighted 17-dot: 0.0625*sum(all 17) + (2-0.0625)*center  (Wc0=2, rest 1/16)
__device__ __forceinline__ float wdot17(const float* __restrict__ a,
                                        const float* __restrict__ b) {
    float full = 0.0f;
    #pragma unroll
    for (int c = 0; c < 4; ++c) {
        const float4 av = *(const float4*)&a[c * 4];
        const float4 bv = *(const float4*)&b[c * 4];
        full += av.x * bv.x + av.y * bv.y + av.z * bv.z + av.w * bv.w;
    }
    full += a[16] * b[16];
    return 0.0625f * full + 1.9375f * a[0] * b[0];
}

// FOUR WAVES PER BATCH (256-thread blocks, grid=1024) -- R10 retry with the
// spill fixed. R10's __launch_bounds__(256,4) capped VGPR at 64 -> register
// spills (FETCH 3.2MB->294MB scratch traffic, VALUBusy 19%). This version
// declares (256,2): allocator cap >=256, compiler lands ~104 VGPR (R8's
// count for identical phase bodies); 104<=128 still permits 4 waves/SIMD at
// RUNTIME (m69: 16 waves/CU at VGPR<=128; LDS 4x11KB=45KB/CU). Body is
// byte-identical to R10's correctness-verified kernel.
//   A[w0 chol8] B[rows 4w..4w+3/wave, 16 on w3; L1+L2 same-wave per row]
//   C[w0 dxT, w1 ypT] D[w0 Ppred | w2 Pxy | w3 Sy+cofactor] E[w0 main, w1 qe]
__global__ __launch_bounds__(256, 2)
void ukf_kernel(const float* __restrict__ X0, const float* __restrict__ U,
                const float* __restrict__ Y,  const float* __restrict__ W1,
                const float* __restrict__ B1, const float* __restrict__ W2,
                const float* __restrict__ B2, const float* __restrict__ HM,
                const float* __restrict__ LQ, const float* __restrict__ LR,
                const float* __restrict__ LP0, float* __restrict__ out)
{
    const int tid  = threadIdx.x;
    const int wid  = tid >> 6;        // 0..3
    const int lane = tid & 63;
    const int b    = blockIdx.x;
    const int k8   = lane & 7;        // column / j8
    const int g8   = lane >> 3;       // replica group / i8
    const int i8   = g8;
    const int j8   = k8;
    const int h32  = lane & 31;
    const int p2   = lane >> 5;       // half-wave (L1 row parity)
    const int m4   = lane & 3;
    const int sy   = lane >> 2;

    __shared__ __align__(16) float u_sh[T_LEN * 2];
    __shared__ __align__(16) float y_sh[T_LEN * 4];
    __shared__ __align__(16) float pts_sh[17 * 8];
    __shared__ __align__(16) float hid_sh[17 * HST];
    __shared__ __align__(16) float pf_sh[17 * 8];
    __shared__ __align__(16) float dxT_sh[8 * TS];   // dxT[d][s]
    __shared__ __align__(16) float ypT_sh[4 * TS];   // ypT[m][s]
    __shared__ __align__(16) float xp_sh[8];
    __shared__ __align__(16) float ypred_sh[4];
    __shared__ __align__(16) float Sy_sh[16];
    __shared__ __align__(16) float Si_sh[16];
    __shared__ __align__(16) float Pxy_sh[32];
    __shared__ __align__(16) float Pp_sh[64];

    // ---- one-time staging (256 threads) ----
    for (int k = tid; k < T_LEN * 2; k += 256) u_sh[k] = U[(size_t)b * (T_LEN * 2) + k];
    for (int k = tid; k < T_LEN * 4; k += 256) y_sh[k] = Y[(size_t)b * (T_LEN * 4) + k];

    float w1r[10];
    #pragma unroll
    for (int d = 0; d < 10; ++d) w1r[d] = W1[d * 32 + h32];
    const float b1r = B1[h32];
    float w2r[32];
    #pragma unroll
    for (int h = 0; h < 32; ++h) w2r[h] = W2[h * 8 + k8];
    const float b2r = B2[k8];
    float hmr[8];                              // wave1 only (ypT)
    #pragma unroll
    for (int d = 0; d < 8; ++d) hmr[d] = HM[m4 * 8 + d];

    const float qdiag = softplus_f(LQ[i8]);    // w0 Ppred
    const float rdiag = softplus_f(LR[m4]);    // w3 Sy

    const size_t Xbase = (size_t)b * T_LEN * 8;
    const size_t Pbase = (size_t)B_LEN * T_LEN * 8  + (size_t)b * T_LEN * 64;
    const size_t qbase = (size_t)B_LEN * T_LEN * 72 + (size_t)b * T_LEN;
    const size_t rbase = (size_t)B_LEN * T_LEN * 73 + (size_t)b * T_LEN;

    // ---- persistent register state (w0): x replicated, P column k8 ----
    float xn[8], Pc[8];
    {
        const float4 xa = *(const float4*)&X0[b * 8];
        const float4 xb = *(const float4*)&X0[b * 8 + 4];
        xn[0] = xa.x; xn[1] = xa.y; xn[2] = xa.z; xn[3] = xa.w;
        xn[4] = xb.x; xn[5] = xb.y; xn[6] = xb.z; xn[7] = xb.w;
        const float p0k = softplus_f(LP0[k8]);
        #pragma unroll
        for (int i = 0; i < 8; ++i) Pc[i] = (i == k8) ? p0k : 0.0f;
    }
    if (wid == 0) {
        out[Pbase + lane] = Pc[g8];                  // coalesced 64-lane P store
        if (lane == 0) {
            *(float4*)&out[Xbase]     = make_float4(xn[0], xn[1], xn[2], xn[3]);
            *(float4*)&out[Xbase + 4] = make_float4(xn[4], xn[5], xn[6], xn[7]);
            out[qbase] = 0.0f; out[rbase] = 0.0f;
        }
    }

    for (int t = 1; t < T_LEN; ++t) {
        // ===== Phase A [w0]: branchless column-chol8 of 8P+jitter -> pts =====
        if (wid == 0) {
            float a[8];
            #pragma unroll
            for (int i = 0; i < 8; ++i) a[i] = 8.0f * Pc[i] + ((i == k8) ? 1e-4f : 0.0f);
            #pragma unroll
            for (int j = 0; j < 8; ++j) {
                const float dj = lane_bcast(a[j], j);
                const float rv = fast_rsq(dj);
                const float sc = (k8 == j) ? rv : 1.0f;
                const float tc = (k8 > j) ? a[j] * (rv * rv) : 0.0f;
                float u[8];
                #pragma unroll
                for (int i = j + 1; i < 8; ++i) u[i] = lane_bcast(a[i], j);
                #pragma unroll
                for (int i = j + 1; i < 8; ++i) a[i] = sc * a[i] - tc * u[i];
                a[j] = (k8 == j) ? dj * rv : a[j];
            }
            float Lc[8];
            #pragma unroll
            for (int i = 0; i < 8; ++i) Lc[i] = (i >= k8) ? a[i] : 0.0f;
            if (g8 == 0) {
                *(float4*)&pts_sh[(1 + k8) * 8] =
                    make_float4(xn[0] + Lc[0], xn[1] + Lc[1], xn[2] + Lc[2], xn[3] + Lc[3]);
                *(float4*)&pts_sh[(1 + k8) * 8 + 4] =
                    make_float4(xn[4] + Lc[4], xn[5] + Lc[5], xn[6] + Lc[6], xn[7] + Lc[7]);
            } else if (g8 == 1) {
                *(float4*)&pts_sh[(9 + k8) * 8] =
                    make_float4(xn[0] - Lc[0], xn[1] - Lc[1], xn[2] - Lc[2], xn[3] - Lc[3]);
                *(float4*)&pts_sh[(9 + k8) * 8 + 4] =
                    make_float4(xn[4] - Lc[4], xn[5] - Lc[5], xn[6] - Lc[6], xn[7] - Lc[7]);
            } else if (g8 == 2 && k8 == 0) {
                *(float4*)&pts_sh[0] = make_float4(xn[0], xn[1], xn[2], xn[3]);
                *(float4*)&pts_sh[4] = make_float4(xn[4], xn[5], xn[6], xn[7]);
            }
        }
        __syncthreads();   // b1: pts ready

        // ===== Phase B [all 4]: L1+L2 on rows 4*wid..4*wid+3 (w3: +row 16) ====
        {
            const float u0 = u_sh[(t - 1) * 2 + 0];
            const float u1 = u_sh[(t - 1) * 2 + 1];
            const float ub = b1r + u0 * w1r[8] + u1 * w1r[9];
            #pragma unroll
            for (int p = 0; p < 2; ++p) {
                const int s = 4 * wid + 2 * p + p2;           // rows 4w..4w+3
                const float4 pa = *(const float4*)&pts_sh[s * 8];
                const float4 pb = *(const float4*)&pts_sh[s * 8 + 4];
                float acc = ub
                    + pa.x * w1r[0] + pa.y * w1r[1] + pa.z * w1r[2] + pa.w * w1r[3]
                    + pb.x * w1r[4] + pb.y * w1r[5] + pb.z * w1r[6] + pb.w * w1r[7];
                hid_sh[s * HST + h32] = fast_tanh(acc);
            }
            if (wid == 3 && p2 == 0) {                        // row 16
                const float4 pa = *(const float4*)&pts_sh[16 * 8];
                const float4 pb = *(const float4*)&pts_sh[16 * 8 + 4];
                float acc = ub
                    + pa.x * w1r[0] + pa.y * w1r[1] + pa.z * w1r[2] + pa.w * w1r[3]
                    + pb.x * w1r[4] + pb.y * w1r[5] + pb.z * w1r[6] + pb.w * w1r[7];
                hid_sh[16 * HST + h32] = fast_tanh(acc);
            }
            // L2 on own-wave rows (same-wave DS in-order: no barrier)
            if (g8 < 4) {
                const int srow = 4 * wid + g8;
                float acc = b2r;
                #pragma unroll
                for (int h = 0; h < 32; h += 4) {
                    const float4 hv = *(const float4*)&hid_sh[srow * HST + h];
                    acc += hv.x * w2r[h] + hv.y * w2r[h + 1] + hv.z * w2r[h + 2] + hv.w * w2r[h + 3];
                }
                pf_sh[srow * 8 + k8] = pts_sh[srow * 8 + k8] + acc;
            } else if (wid == 3 && g8 == 4) {                 // row 16, col k8
                float a16 = b2r;
                #pragma unroll
                for (int h = 0; h < 32; h += 4) {
                    const float4 hv = *(const float4*)&hid_sh[16 * HST + h];
                    a16 += hv.x * w2r[h] + hv.y * w2r[h + 1] + hv.z * w2r[h + 2] + hv.w * w2r[h + 3];
                }
                pf_sh[16 * 8 + k8] = pts_sh[16 * 8 + k8] + a16;
            }
        }
        __syncthreads();   // b2: pf ready

        // ===== Phase C [w0]: x_pred + dxT ; [w1]: y_pts + ypred + ypT =========
        if (wid == 0) {
            const float v0   = pf_sh[i8 * 8 + j8];
            const float v1   = pf_sh[(8 + i8) * 8 + j8];
            const float pf16 = (i8 == 0) ? pf_sh[16 * 8 + j8] : 0.0f;
            float part = ((i8 == 0) ? pf16 : v0) + v1;        // s=16 replaces s=0
            part += __shfl_xor(part, 8);
            part += __shfl_xor(part, 16);
            part += __shfl_xor(part, 32);
            const float xp = part * 0.0625f;
            if (i8 == 0) xp_sh[j8] = xp;
            dxT_sh[j8 * TS + i8]       = v0 - xp;             // dxT[d][s]
            dxT_sh[j8 * TS + 8 + i8]   = v1 - xp;
            if (i8 == 0) dxT_sh[j8 * TS + 16] = pf16 - xp;
        } else if (wid == 1) {
            float yv0, yv16 = 0.0f;
            {
                const float4 pa = *(const float4*)&pf_sh[sy * 8];
                const float4 pb = *(const float4*)&pf_sh[sy * 8 + 4];
                yv0 = pa.x * hmr[0] + pa.y * hmr[1] + pa.z * hmr[2] + pa.w * hmr[3]
                    + pb.x * hmr[4] + pb.y * hmr[5] + pb.z * hmr[6] + pb.w * hmr[7];
            }
            if (sy == 0) {
                const float4 pa = *(const float4*)&pf_sh[16 * 8];
                const float4 pb = *(const float4*)&pf_sh[16 * 8 + 4];
                yv16 = pa.x * hmr[0] + pa.y * hmr[1] + pa.z * hmr[2] + pa.w * hmr[3]
                     + pb.x * hmr[4] + pb.y * hmr[5] + pb.z * hmr[6] + pb.w * hmr[7];
            }
            float py = (sy == 0) ? yv16 : yv0;
            py += __shfl_xor(py, 4);
            py += __shfl_xor(py, 8);
            py += __shfl_xor(py, 16);
            py += __shfl_xor(py, 32);
            const float ypred = py * 0.0625f;
            if (lane < 4) ypred_sh[lane] = ypred;
            ypT_sh[m4 * TS + sy] = yv0 - ypred;               // ypT[m][s]
            if (sy == 0) ypT_sh[m4 * TS + 16] = yv16 - ypred;
        }
        __syncthreads();   // b3: dxT, ypT, xp, ypred ready

        // ===== Phase D: [w0] Ppred ; [w2] Pxy ; [w3] Sy -> cofactor Si ========
        float Ppc[8];
        if (wid == 0) {
            const float Ppred = wdot17(&dxT_sh[i8 * TS], &dxT_sh[j8 * TS])
                              + ((i8 == j8) ? (qdiag + 1e-4f) : 0.0f);
            Pp_sh[lane] = Ppred;
            // Pp exactly symmetric -> column k8 == row k8 (contiguous):
            // 2x ds_read_b128, 2-way bank alias (free), in-wave ordering.
            const float4 pa = *(const float4*)&Pp_sh[k8 * 8];
            const float4 pb = *(const float4*)&Pp_sh[k8 * 8 + 4];
            Ppc[0]=pa.x; Ppc[1]=pa.y; Ppc[2]=pa.z; Ppc[3]=pa.w;
            Ppc[4]=pb.x; Ppc[5]=pb.y; Ppc[6]=pb.z; Ppc[7]=pb.w;
        } else if (wid == 2) {
            // Pxy(ii=sy, mm=m4) on lanes<32; dxT/ypT reads fenced by b3
            if (lane < 32)
                Pxy_sh[lane] = wdot17(&dxT_sh[sy * TS], &ypT_sh[m4 * TS]);
        } else if (wid == 3) {
            // Sy on lanes<16 (sy=row 0..3, m4=col); then cofactor inverse
            if (lane < 16)
                Sy_sh[lane] = wdot17(&ypT_sh[sy * TS], &ypT_sh[m4 * TS])
                            + ((sy == m4) ? rdiag : 0.0f);
            // parallel cofactor inverse (R7-verified); Sy_sh read in-wave
            float cof;
            {
                const int i4 = sy & 3;
                const int j4 = m4;
                const int r0 = (i4 == 0) ? 1 : 0;
                const int r1 = (i4 <= 1) ? 2 : 1;
                const int rr = (i4 <= 2) ? 3 : 2;
                const int c0 = (j4 == 0) ? 1 : 0;
                const int c1 = (j4 <= 1) ? 2 : 1;
                const int cc = (j4 <= 2) ? 3 : 2;
                const float m00 = Sy_sh[r0 * 4 + c0], m01 = Sy_sh[r0 * 4 + c1], m02 = Sy_sh[r0 * 4 + cc];
                const float m10 = Sy_sh[r1 * 4 + c0], m11 = Sy_sh[r1 * 4 + c1], m12 = Sy_sh[r1 * 4 + cc];
                const float m20 = Sy_sh[rr * 4 + c0], m21 = Sy_sh[rr * 4 + c1], m22 = Sy_sh[rr * 4 + cc];
                const float d3 = m00 * (m11 * m22 - m12 * m21)
                               - m01 * (m10 * m22 - m12 * m20)
                               + m02 * (m10 * m21 - m11 * m20);
                cof = (((i4 + j4) & 1) ? -d3 : d3);
            }
            const float c0b = lane_bcast(cof, 0);
            const float c1b = lane_bcast(cof, 1);
            const float c2b = lane_bcast(cof, 2);
            const float c3b = lane_bcast(cof, 3);
            const float4 sy0 = *(const float4*)&Sy_sh[0];
            const float det = sy0.x * c0b + sy0.y * c1b + sy0.z * c2b + sy0.w * c3b;
            if (lane == 0) out[rbase + t] = 0.5f * __logf(det);
            const float rdet = fast_rcp(det);
            if (lane < 16) Si_sh[lane] = cof * rdet;
        }
        __syncthreads();   // b4: Pp / Si / Pxy ready

        // ===== Phase E: [w0] kk -> P_new(symmetric form), x_new ; [w1] qe =====
        if (wid == 0) {
            float Si[16];
            {
                const float4 a0 = *(const float4*)&Si_sh[0];
                const float4 a1 = *(const float4*)&Si_sh[4];
                const float4 a2 = *(const float4*)&Si_sh[8];
                const float4 a3 = *(const float4*)&Si_sh[12];
                Si[0]=a0.x;  Si[1]=a0.y;  Si[2]=a0.z;  Si[3]=a0.w;
                Si[4]=a1.x;  Si[5]=a1.y;  Si[6]=a1.z;  Si[7]=a1.w;
                Si[8]=a2.x;  Si[9]=a2.y;  Si[10]=a2.z; Si[11]=a2.w;
                Si[12]=a3.x; Si[13]=a3.y; Si[14]=a3.z; Si[15]=a3.w;
            }
            const float4 pr = *(const float4*)&Pxy_sh[k8 * 4];     // Pxy row k8
            float kk[4];
            #pragma unroll
            for (int aa = 0; aa < 4; ++aa)
                kk[aa] = pr.x * Si[0 * 4 + aa] + pr.y * Si[1 * 4 + aa]
                       + pr.z * Si[2 * 4 + aa] + pr.w * Si[3 * 4 + aa];
            // all 8 Pxy rows (broadcast LDS reads, compile-time indexed regs)
            float Pr[32];
            {
                const float4 q0 = *(const float4*)&Pxy_sh[0];
                const float4 q1 = *(const float4*)&Pxy_sh[4];
                const float4 q2 = *(const float4*)&Pxy_sh[8];
                const float4 q3 = *(const float4*)&Pxy_sh[12];
                const float4 q4 = *(const float4*)&Pxy_sh[16];
                const float4 q5 = *(const float4*)&Pxy_sh[20];
                const float4 q6 = *(const float4*)&Pxy_sh[24];
                const float4 q7 = *(const float4*)&Pxy_sh[28];
                Pr[0]=q0.x;  Pr[1]=q0.y;  Pr[2]=q0.z;  Pr[3]=q0.w;
                Pr[4]=q1.x;  Pr[5]=q1.y;  Pr[6]=q1.z;  Pr[7]=q1.w;
                Pr[8]=q2.x;  Pr[9]=q2.y;  Pr[10]=q2.z; Pr[11]=q2.w;
                Pr[12]=q3.x; Pr[13]=q3.y; Pr[14]=q3.z; Pr[15]=q3.w;
                Pr[16]=q4.x; Pr[17]=q4.y; Pr[18]=q4.z; Pr[19]=q4.w;
                Pr[20]=q5.x; Pr[21]=q5.y; Pr[22]=q5.z; Pr[23]=q5.w;
                Pr[24]=q6.x; Pr[25]=q6.y; Pr[26]=q6.z; Pr[27]=q6.w;
                Pr[28]=q7.x; Pr[29]=q7.y; Pr[30]=q7.z; Pr[31]=q7.w;
            }
            // P_new column k8: Pc[i] = Ppc[i] - dot(kk, Pxy row i)  (+ jitter)
            #pragma unroll
            for (int i = 0; i < 8; ++i) {
                const float m = kk[0] * Pr[i * 4 + 0] + kk[1] * Pr[i * 4 + 1]
                              + kk[2] * Pr[i * 4 + 2] + kk[3] * Pr[i * 4 + 3];
                Pc[i] = Ppc[i] - m + ((i == k8) ? 1e-4f : 0.0f);
            }
            // x_new: own row k8 then broadcast (lane r<8 has k8==r)
            const float4 yt = *(const float4*)&y_sh[t * 4];
            const float4 yp = *(const float4*)&ypred_sh[0];
            const float in0 = yt.x - yp.x, in1 = yt.y - yp.y;
            const float in2 = yt.z - yp.z, in3 = yt.w - yp.w;
            const float xo = xp_sh[k8]
                           + kk[0] * in0 + kk[1] * in1 + kk[2] * in2 + kk[3] * in3;
            #pragma unroll
            for (int i = 0; i < 8; ++i) xn[i] = lane_bcast(xo, i);
            // stores: coalesced 64-lane P store (lane (g8,k8) owns P[g8][k8])
            out[Pbase + (size_t)t * 64 + lane] = Pc[g8];
            if (lane == 0) {
                *(float4*)&out[Xbase + (size_t)t * 8]     = make_float4(xn[0], xn[1], xn[2], xn[3]);
                *(float4*)&out[Xbase + (size_t)t * 8 + 4] = make_float4(xn[4], xn[5], xn[6], xn[7]);
            }
        } else if (wid == 1) {
            // qe = 0.5 slogdet(P_pred): branchless column LDL; aq = Pp row k8
            float aq[8];
            {
                const float4 pa = *(const float4*)&Pp_sh[k8 * 8];
                const float4 pb = *(const float4*)&Pp_sh[k8 * 8 + 4];
                aq[0]=pa.x; aq[1]=pa.y; aq[2]=pa.z; aq[3]=pa.w;
                aq[4]=pb.x; aq[5]=pb.y; aq[6]=pb.z; aq[7]=pb.w;
            }
            float qe = 0.0f;
            #pragma unroll
            for (int j = 0; j < 8; ++j) {
                const float dj  = lane_bcast(aq[j], j);
                qe += __logf(dj);
                const float rv2 = fast_rcp(dj);
                const float tq  = (k8 > j) ? aq[j] * rv2 : 0.0f;
                float u[8];
                #pragma unroll
                for (int i = j + 1; i < 8; ++i) u[i] = lane_bcast(aq[i], j);
                #pragma unroll
                for (int i = j + 1; i < 8; ++i) aq[i] = fmaf(-tq, u[i], aq[i]);
            }
            if (lane == 0) out[qbase + t] = 0.5f * qe;
        }
        // no trailing barrier: next-step hazards are covered by b1..b4 ordering
    }
}

extern "C" void kernel_launch(void* const* d_in, const int* in_sizes, int n_in,
                              void* d_out, int out_size, void* d_ws, size_t ws_size,
                              hipStream_t stream) {
    (void)in_sizes; (void)n_in; (void)out_size; (void)d_ws; (void)ws_size;
    const float* X0 = (const float*)d_in[0];
    const float* U  = (const float*)d_in[1];
    const float* Y  = (const float*)d_in[2];
    const float* W1 = (const float*)d_in[3];
    const float* B1 = (const float*)d_in[4];
    const float* W2 = (const float*)d_in[5];
    const float* B2 = (const float*)d_in[6];
    const float* HM = (const float*)d_in[7];
    const float* LQ = (const float*)d_in[8];
    const float* LR = (const float*)d_in[9];
    const float* LP0 = (const float*)d_in[10];
    float* out = (float*)d_out;
    ukf_kernel<<<dim3(B_LEN), dim3(256), 0, stream>>>(X0, U, Y, W1, B1, W2, B2,
                                                      HM, LQ, LR, LP0, out);
}

// Round 12
// 801.110 us; speedup vs baseline: 3.1687x; 1.7821x over previous
//
#include <hip/hip_runtime.h>
#include <math.h>

#define B_LEN 1024
#define T_LEN 256
#define HST 36   // hid_sh leading stride keeps float4 access conflict-light
#define TS 20    // dxT/ypT row stride (17 used + 3 pad): banks 20*r%32 distinct

__device__ __forceinline__ float fast_rcp(float x) { return __builtin_amdgcn_rcpf(x); }
__device__ __forceinline__ float fast_rsq(float x) { return __builtin_amdgcn_rsqf(x); }
__device__ __forceinline__ float lane_bcast(float v, int l) {
    return __int_as_float(__builtin_amdgcn_readlane(__float_as_int(v), l));
}
__device__ __forceinline__ float fast_tanh(float x) {
    float e = __expf(2.0f * x);
    return 1.0f - 2.0f * fast_rcp(e + 1.0f);
}
__device__ __forceinline__ float softplus_f(float x) {
    return (x > 20.0f) ? x : log1pf(expf(x));
}
// weighted 17-dot: 0.0625*sum(all 17) + (2-0.0625)*center  (Wc0=2, rest 1/16)
__device__ __forceinline__ float wdot17(const float* __restrict__ a,
                                        const float* __restrict__ b) {
    float full = 0.0f;
    #pragma unroll
    for (int c = 0; c < 4; ++c) {
        const float4 av = *(const float4*)&a[c * 4];
        const float4 bv = *(const float4*)&b[c * 4];
        full += av.x * bv.x + av.y * bv.y + av.z * bv.z + av.w * bv.w;
    }
    full += a[16] * b[16];
    return 0.0625f * full + 1.9375f * a[0] * b[0];
}

// R8 verified base (750us; 128 threads, 2 waves, 4 barriers) + ONE graft:
// (Q1) deferred qe: w1's serial qe-LDL (~300cyc readlane+log chain, the
//      E-phase max) moves into the A-phase slot of the NEXT step, where w1
//      previously idled behind w0's chol8 (~400cyc). The two serial poles
//      now run concurrently; E's w1 side is empty.
//      Hazards: Pp_sh written D(t) pre-b4(t); w1 reads in A(t+1) post-b4(t);
//      next overwrite D(t+1) is post-b3(t+1), and w0 cannot pass b1(t+1)
//      until w1's read drained. Edges: qe(0)=0 at init; A(t) computes
//      qe(t-1) for t>=2; qe(255) post-loop (Pp_sh still valid).
// R9-R11 closed the occupancy direction: de-phasing neutral, 4-wave/batch
// worse (even spill-free) -- 2 waves/SIMD with this structure is optimal.
__global__ __launch_bounds__(128, 2)
void ukf_kernel(const float* __restrict__ X0, const float* __restrict__ U,
                const float* __restrict__ Y,  const float* __restrict__ W1,
                const float* __restrict__ B1, const float* __restrict__ W2,
                const float* __restrict__ B2, const float* __restrict__ HM,
                const float* __restrict__ LQ, const float* __restrict__ LR,
                const float* __restrict__ LP0, float* __restrict__ out)
{
    const int tid  = threadIdx.x;
    const int wid  = tid >> 6;
    const int lane = tid & 63;
    const int b    = blockIdx.x;
    const int k8   = lane & 7;        // column / j8
    const int g8   = lane >> 3;       // replica group / i8
    const int i8   = g8;
    const int j8   = k8;
    const int h32  = lane & 31;
    const int p2   = lane >> 5;       // half-wave (L1 row parity)
    const int m4   = lane & 3;
    const int sy   = lane >> 2;

    __shared__ __align__(16) float u_sh[T_LEN * 2];
    __shared__ __align__(16) float y_sh[T_LEN * 4];
    __shared__ __align__(16) float pts_sh[17 * 8];
    __shared__ __align__(16) float hid_sh[17 * HST];
    __shared__ __align__(16) float pf_sh[17 * 8];
    __shared__ __align__(16) float dxT_sh[8 * TS];   // dxT[d][s]
    __shared__ __align__(16) float ypT_sh[4 * TS];   // ypT[m][s]
    __shared__ __align__(16) float xp_sh[8];
    __shared__ __align__(16) float ypred_sh[4];
    __shared__ __align__(16) float Sy_sh[16];
    __shared__ __align__(16) float Si_sh[16];
    __shared__ __align__(16) float Pxy_sh[32];
    __shared__ __align__(16) float Pp_sh[64];

    // ---- one-time staging ----
    for (int k = tid; k < T_LEN * 2; k += 128) u_sh[k] = U[(size_t)b * (T_LEN * 2) + k];
    for (int k = tid; k < T_LEN * 4; k += 128) y_sh[k] = Y[(size_t)b * (T_LEN * 4) + k];

    float w1r[10];
    #pragma unroll
    for (int d = 0; d < 10; ++d) w1r[d] = W1[d * 32 + h32];
    const float b1r = B1[h32];
    float w2r[32];
    #pragma unroll
    for (int h = 0; h < 32; ++h) w2r[h] = W2[h * 8 + k8];
    const float b2r = B2[k8];
    float hmr[8];                              // wave1 only
    #pragma unroll
    for (int d = 0; d < 8; ++d) hmr[d] = HM[m4 * 8 + d];

    const float qdiag = softplus_f(LQ[i8]);    // w0 Ppred
    const float rdiag = softplus_f(LR[m4]);    // w1 Sy

    const size_t Xbase = (size_t)b * T_LEN * 8;
    const size_t Pbase = (size_t)B_LEN * T_LEN * 8  + (size_t)b * T_LEN * 64;
    const size_t qbase = (size_t)B_LEN * T_LEN * 72 + (size_t)b * T_LEN;
    const size_t rbase = (size_t)B_LEN * T_LEN * 73 + (size_t)b * T_LEN;

    // ---- persistent register state (w0): x replicated, P column k8 ----
    float xn[8], Pc[8];
    {
        const float4 xa = *(const float4*)&X0[b * 8];
        const float4 xb = *(const float4*)&X0[b * 8 + 4];
        xn[0] = xa.x; xn[1] = xa.y; xn[2] = xa.z; xn[3] = xa.w;
        xn[4] = xb.x; xn[5] = xb.y; xn[6] = xb.z; xn[7] = xb.w;
        const float p0k = softplus_f(LP0[k8]);
        #pragma unroll
        for (int i = 0; i < 8; ++i) Pc[i] = (i == k8) ? p0k : 0.0f;
    }
    if (wid == 0) {
        out[Pbase + lane] = Pc[g8];                  // coalesced 64-lane P store
        if (lane == 0) {
            *(float4*)&out[Xbase]     = make_float4(xn[0], xn[1], xn[2], xn[3]);
            *(float4*)&out[Xbase + 4] = make_float4(xn[4], xn[5], xn[6], xn[7]);
            out[qbase] = 0.0f; out[rbase] = 0.0f;
        }
    }

    for (int t = 1; t < T_LEN; ++t) {
        // ===== Phase A [w0]: chol8 -> pts ; [w1]: deferred qe(t-1) LDL ========
        if (wid == 0) {
            float a[8];
            #pragma unroll
            for (int i = 0; i < 8; ++i) a[i] = 8.0f * Pc[i] + ((i == k8) ? 1e-4f : 0.0f);
            #pragma unroll
            for (int j = 0; j < 8; ++j) {
                const float dj = lane_bcast(a[j], j);
                const float rv = fast_rsq(dj);
                const float sc = (k8 == j) ? rv : 1.0f;
                const float tc = (k8 > j) ? a[j] * (rv * rv) : 0.0f;
                float u[8];
                #pragma unroll
                for (int i = j + 1; i < 8; ++i) u[i] = lane_bcast(a[i], j);
                #pragma unroll
                for (int i = j + 1; i < 8; ++i) a[i] = sc * a[i] - tc * u[i];
                a[j] = (k8 == j) ? dj * rv : a[j];
            }
            float Lc[8];
            #pragma unroll
            for (int i = 0; i < 8; ++i) Lc[i] = (i >= k8) ? a[i] : 0.0f;
            if (g8 == 0) {
                *(float4*)&pts_sh[(1 + k8) * 8] =
                    make_float4(xn[0] + Lc[0], xn[1] + Lc[1], xn[2] + Lc[2], xn[3] + Lc[3]);
                *(float4*)&pts_sh[(1 + k8) * 8 + 4] =
                    make_float4(xn[4] + Lc[4], xn[5] + Lc[5], xn[6] + Lc[6], xn[7] + Lc[7]);
            } else if (g8 == 1) {
                *(float4*)&pts_sh[(9 + k8) * 8] =
                    make_float4(xn[0] - Lc[0], xn[1] - Lc[1], xn[2] - Lc[2], xn[3] - Lc[3]);
                *(float4*)&pts_sh[(9 + k8) * 8 + 4] =
                    make_float4(xn[4] - Lc[4], xn[5] - Lc[5], xn[6] - Lc[6], xn[7] - Lc[7]);
            } else if (g8 == 2 && k8 == 0) {
                *(float4*)&pts_sh[0] = make_float4(xn[0], xn[1], xn[2], xn[3]);
                *(float4*)&pts_sh[4] = make_float4(xn[4], xn[5], xn[6], xn[7]);
            }
        } else if (t >= 2) {
            // (Q1) qe(t-1) = 0.5 slogdet(Pp(t-1)): branchless column LDL.
            // Pp_sh valid: written D(t-1) pre-b4(t-1); next write D(t) is
            // post-b3(t), and w0 can't pass b1(t) until this read drains.
            float aq[8];
            {
                const float4 pa = *(const float4*)&Pp_sh[k8 * 8];
                const float4 pb = *(const float4*)&Pp_sh[k8 * 8 + 4];
                aq[0]=pa.x; aq[1]=pa.y; aq[2]=pa.z; aq[3]=pa.w;
                aq[4]=pb.x; aq[5]=pb.y; aq[6]=pb.z; aq[7]=pb.w;
            }
            float qe = 0.0f;
            #pragma unroll
            for (int j = 0; j < 8; ++j) {
                const float dj  = lane_bcast(aq[j], j);
                qe += __logf(dj);
                const float rv2 = fast_rcp(dj);
                const float tq  = (k8 > j) ? aq[j] * rv2 : 0.0f;
                float u[8];
                #pragma unroll
                for (int i = j + 1; i < 8; ++i) u[i] = lane_bcast(aq[i], j);
                #pragma unroll
                for (int i = j + 1; i < 8; ++i) aq[i] = fmaf(-tq, u[i], aq[i]);
            }
            if (lane == 0) out[qbase + (t - 1)] = 0.5f * qe;
        }
        __syncthreads();   // b1: pts ready

        // ===== Phase B [both]: fused L1+L2, per-wave sigma sets ===============
        {
            const float u0 = u_sh[(t - 1) * 2 + 0];
            const float u1 = u_sh[(t - 1) * 2 + 1];
            const float ub = b1r + u0 * w1r[8] + u1 * w1r[9];
            if (wid == 0) {
                #pragma unroll
                for (int p = 0; p < 4; ++p) {
                    const int s = 2 * p + p2;                 // rows 0..7
                    const float4 pa = *(const float4*)&pts_sh[s * 8];
                    const float4 pb = *(const float4*)&pts_sh[s * 8 + 4];
                    float acc = ub
                        + pa.x * w1r[0] + pa.y * w1r[1] + pa.z * w1r[2] + pa.w * w1r[3]
                        + pb.x * w1r[4] + pb.y * w1r[5] + pb.z * w1r[6] + pb.w * w1r[7];
                    hid_sh[s * HST + h32] = fast_tanh(acc);
                }
            } else {
                #pragma unroll
                for (int p = 0; p < 4; ++p) {
                    const int s = 8 + 2 * p + p2;             // rows 8..15
                    const float4 pa = *(const float4*)&pts_sh[s * 8];
                    const float4 pb = *(const float4*)&pts_sh[s * 8 + 4];
                    float acc = ub
                        + pa.x * w1r[0] + pa.y * w1r[1] + pa.z * w1r[2] + pa.w * w1r[3]
                        + pb.x * w1r[4] + pb.y * w1r[5] + pb.z * w1r[6] + pb.w * w1r[7];
                    hid_sh[s * HST + h32] = fast_tanh(acc);
                }
                if (p2 == 0) {                                // row 16
                    const float4 pa = *(const float4*)&pts_sh[16 * 8];
                    const float4 pb = *(const float4*)&pts_sh[16 * 8 + 4];
                    float acc = ub
                        + pa.x * w1r[0] + pa.y * w1r[1] + pa.z * w1r[2] + pa.w * w1r[3]
                        + pb.x * w1r[4] + pb.y * w1r[5] + pb.z * w1r[6] + pb.w * w1r[7];
                    hid_sh[16 * HST + h32] = fast_tanh(acc);
                }
            }
            // L2 on own-wave rows (same-wave DS in-order: no barrier)
            const int srow = (wid == 0) ? g8 : (8 + g8);
            float acc = b2r;
            #pragma unroll
            for (int h = 0; h < 32; h += 4) {
                const float4 hv = *(const float4*)&hid_sh[srow * HST + h];
                acc += hv.x * w2r[h] + hv.y * w2r[h + 1] + hv.z * w2r[h + 2] + hv.w * w2r[h + 3];
            }
            pf_sh[srow * 8 + k8] = pts_sh[srow * 8 + k8] + acc;
            if (wid == 1 && lane < 8) {
                float a16 = b2r;
                #pragma unroll
                for (int h = 0; h < 32; h += 4) {
                    const float4 hv = *(const float4*)&hid_sh[16 * HST + h];
                    a16 += hv.x * w2r[h] + hv.y * w2r[h + 1] + hv.z * w2r[h + 2] + hv.w * w2r[h + 3];
                }
                pf_sh[16 * 8 + lane] = pts_sh[16 * 8 + lane] + a16;
            }
        }
        __syncthreads();   // b2: pf ready

        // ===== Phase C [w0]: x_pred + dxT ; [w1]: y_pts + ypred + ypT =========
        if (wid == 0) {
            const float v0   = pf_sh[i8 * 8 + j8];
            const float v1   = pf_sh[(8 + i8) * 8 + j8];
            const float pf16 = (i8 == 0) ? pf_sh[16 * 8 + j8] : 0.0f;
            float part = ((i8 == 0) ? pf16 : v0) + v1;        // s=16 replaces s=0
            part += __shfl_xor(part, 8);
            part += __shfl_xor(part, 16);
            part += __shfl_xor(part, 32);
            const float xp = part * 0.0625f;
            if (i8 == 0) xp_sh[j8] = xp;
            dxT_sh[j8 * TS + i8]       = v0 - xp;             // dxT[d][s]
            dxT_sh[j8 * TS + 8 + i8]   = v1 - xp;
            if (i8 == 0) dxT_sh[j8 * TS + 16] = pf16 - xp;
        } else {
            float yv0, yv16 = 0.0f;
            {
                const float4 pa = *(const float4*)&pf_sh[sy * 8];
                const float4 pb = *(const float4*)&pf_sh[sy * 8 + 4];
                yv0 = pa.x * hmr[0] + pa.y * hmr[1] + pa.z * hmr[2] + pa.w * hmr[3]
                    + pb.x * hmr[4] + pb.y * hmr[5] + pb.z * hmr[6] + pb.w * hmr[7];
            }
            if (sy == 0) {
                const float4 pa = *(const float4*)&pf_sh[16 * 8];
                const float4 pb = *(const float4*)&pf_sh[16 * 8 + 4];
                yv16 = pa.x * hmr[0] + pa.y * hmr[1] + pa.z * hmr[2] + pa.w * hmr[3]
                     + pb.x * hmr[4] + pb.y * hmr[5] + pb.z * hmr[6] + pb.w * hmr[7];
            }
            float py = (sy == 0) ? yv16 : yv0;
            py += __shfl_xor(py, 4);
            py += __shfl_xor(py, 8);
            py += __shfl_xor(py, 16);
            py += __shfl_xor(py, 32);
            const float ypred = py * 0.0625f;
            if (lane < 4) ypred_sh[lane] = ypred;
            ypT_sh[m4 * TS + sy] = yv0 - ypred;               // ypT[m][s]
            if (sy == 0) ypT_sh[m4 * TS + 16] = yv16 - ypred;
        }
        __syncthreads();   // b3: dxT, ypT, xp, ypred ready

        // ===== Phase D: [w0] Ppred only ; [w1] merged Pxy+Sy -> cofactor Si ===
        float Ppc[8];
        if (wid == 0) {
            const float Ppred = wdot17(&dxT_sh[i8 * TS], &dxT_sh[j8 * TS])
                              + ((i8 == j8) ? (qdiag + 1e-4f) : 0.0f);
            Pp_sh[lane] = Ppred;
            // Pp exactly symmetric -> column k8 == row k8 (contiguous):
            // 2x ds_read_b128, 2-way bank alias (free), in-wave ordering.
            const float4 pa = *(const float4*)&Pp_sh[k8 * 8];
            const float4 pb = *(const float4*)&Pp_sh[k8 * 8 + 4];
            Ppc[0]=pa.x; Ppc[1]=pa.y; Ppc[2]=pa.z; Ppc[3]=pa.w;
            Ppc[4]=pb.x; Ppc[5]=pb.y; Ppc[6]=pb.z; Ppc[7]=pb.w;
        } else {
            // merged round (R2-verified): lanes<32 -> Pxy(ii=sy, mm=m4);
            // lanes 32..47 -> Sy(r2, m4). dxT read fenced by b3.
            const int r2 = (lane < 32) ? sy : (sy & 3);
            const float* pa2 = (lane < 32) ? &dxT_sh[r2 * TS] : &ypT_sh[r2 * TS];
            float v2 = wdot17(pa2, &ypT_sh[m4 * TS]);
            v2 += ((lane >= 32) && (r2 == m4)) ? rdiag : 0.0f;
            if (lane < 32)      Pxy_sh[lane] = v2;
            else if (lane < 48) Sy_sh[r2 * 4 + m4] = v2;
            // parallel cofactor inverse (R7-verified); Sy_sh read in-wave
            float cof;
            {
                const int i4 = sy & 3;
                const int j4 = m4;
                const int r0 = (i4 == 0) ? 1 : 0;
                const int r1 = (i4 <= 1) ? 2 : 1;
                const int rr = (i4 <= 2) ? 3 : 2;
                const int c0 = (j4 == 0) ? 1 : 0;
                const int c1 = (j4 <= 1) ? 2 : 1;
                const int cc = (j4 <= 2) ? 3 : 2;
                const float m00 = Sy_sh[r0 * 4 + c0], m01 = Sy_sh[r0 * 4 + c1], m02 = Sy_sh[r0 * 4 + cc];
                const float m10 = Sy_sh[r1 * 4 + c0], m11 = Sy_sh[r1 * 4 + c1], m12 = Sy_sh[r1 * 4 + cc];
                const float m20 = Sy_sh[rr * 4 + c0], m21 = Sy_sh[rr * 4 + c1], m22 = Sy_sh[rr * 4 + cc];
                const float d3 = m00 * (m11 * m22 - m12 * m21)
                               - m01 * (m10 * m22 - m12 * m20)
                               + m02 * (m10 * m21 - m11 * m20);
                cof = (((i4 + j4) & 1) ? -d3 : d3);
            }
            const float c0b = lane_bcast(cof, 0);
            const float c1b = lane_bcast(cof, 1);
            const float c2b = lane_bcast(cof, 2);
            const float c3b = lane_bcast(cof, 3);
            const float4 sy0 = *(const float4*)&Sy_sh[0];
            const float det = sy0.x * c0b + sy0.y * c1b + sy0.z * c2b + sy0.w * c3b;
            if (lane == 0) out[rbase + t] = 0.5f * __logf(det);
            const float rdet = fast_rcp(det);
            if (lane < 16) Si_sh[lane] = cof * rdet;
        }
        __syncthreads();   // b4: Pp / Si / Pxy ready

        // ===== Phase E: [w0] kk -> P_new(symmetric form), x_new ; [w1] idle ===
        if (wid == 0) {
            float Si[16];
            {
                const float4 a0 = *(const float4*)&Si_sh[0];
                const float4 a1 = *(const float4*)&Si_sh[4];
                const float4 a2 = *(const float4*)&Si_sh[8];
                const float4 a3 = *(const float4*)&Si_sh[12];
                Si[0]=a0.x;  Si[1]=a0.y;  Si[2]=a0.z;  Si[3]=a0.w;
                Si[4]=a1.x;  Si[5]=a1.y;  Si[6]=a1.z;  Si[7]=a1.w;
                Si[8]=a2.x;  Si[9]=a2.y;  Si[10]=a2.z; Si[11]=a2.w;
                Si[12]=a3.x; Si[13]=a3.y; Si[14]=a3.z; Si[15]=a3.w;
            }
            const float4 pr = *(const float4*)&Pxy_sh[k8 * 4];     // Pxy row k8
            float kk[4];
            #pragma unroll
            for (int aa = 0; aa < 4; ++aa)
                kk[aa] = pr.x * Si[0 * 4 + aa] + pr.y * Si[1 * 4 + aa]
                       + pr.z * Si[2 * 4 + aa] + pr.w * Si[3 * 4 + aa];
            // all 8 Pxy rows (broadcast LDS reads, compile-time indexed regs)
            float Pr[32];
            {
                const float4 q0 = *(const float4*)&Pxy_sh[0];
                const float4 q1 = *(const float4*)&Pxy_sh[4];
                const float4 q2 = *(const float4*)&Pxy_sh[8];
                const float4 q3 = *(const float4*)&Pxy_sh[12];
                const float4 q4 = *(const float4*)&Pxy_sh[16];
                const float4 q5 = *(const float4*)&Pxy_sh[20];
                const float4 q6 = *(const float4*)&Pxy_sh[24];
                const float4 q7 = *(const float4*)&Pxy_sh[28];
                Pr[0]=q0.x;  Pr[1]=q0.y;  Pr[2]=q0.z;  Pr[3]=q0.w;
                Pr[4]=q1.x;  Pr[5]=q1.y;  Pr[6]=q1.z;  Pr[7]=q1.w;
                Pr[8]=q2.x;  Pr[9]=q2.y;  Pr[10]=q2.z; Pr[11]=q2.w;
                Pr[12]=q3.x; Pr[13]=q3.y; Pr[14]=q3.z; Pr[15]=q3.w;
                Pr[16]=q4.x; Pr[17]=q4.y; Pr[18]=q4.z; Pr[19]=q4.w;
                Pr[20]=q5.x; Pr[21]=q5.y; Pr[22]=q5.z; Pr[23]=q5.w;
                Pr[24]=q6.x; Pr[25]=q6.y; Pr[26]=q6.z; Pr[27]=q6.w;
                Pr[28]=q7.x; Pr[29]=q7.y; Pr[30]=q7.z; Pr[31]=q7.w;
            }
            // P_new column k8: Pc[i] = Ppc[i] - dot(kk, Pxy row i)  (+ jitter)
            #pragma unroll
            for (int i = 0; i < 8; ++i) {
                const float m = kk[0] * Pr[i * 4 + 0] + kk[1] * Pr[i * 4 + 1]
                              + kk[2] * Pr[i * 4 + 2] + kk[3] * Pr[i * 4 + 3];
                Pc[i] = Ppc[i] - m + ((i == k8) ? 1e-4f : 0.0f);
            }
            // x_new: own row k8 then broadcast (lane r<8 has k8==r)
            const float4 yt = *(const float4*)&y_sh[t * 4];
            const float4 yp = *(const float4*)&ypred_sh[0];
            const float in0 = yt.x - yp.x, in1 = yt.y - yp.y;
            const float in2 = yt.z - yp.z, in3 = yt.w - yp.w;
            const float xo = xp_sh[k8]
                           + kk[0] * in0 + kk[1] * in1 + kk[2] * in2 + kk[3] * in3;
            #pragma unroll
            for (int i = 0; i < 8; ++i) xn[i] = lane_bcast(xo, i);
            // stores: coalesced 64-lane P store (lane (g8,k8) owns P[g8][k8])
            out[Pbase + (size_t)t * 64 + lane] = Pc[g8];
            if (lane == 0) {
                *(float4*)&out[Xbase + (size_t)t * 8]     = make_float4(xn[0], xn[1], xn[2], xn[3]);
                *(float4*)&out[Xbase + (size_t)t * 8 + 4] = make_float4(xn[4], xn[5], xn[6], xn[7]);
            }
        }
        // no trailing barrier: next-step hazards are covered by b1..b4 ordering
    }

    // final deferred qe(T-1) [w1]: Pp_sh last written D(255), still valid
    if (wid == 1) {
        float aq[8];
        {
            const float4 pa = *(const float4*)&Pp_sh[k8 * 8];
            const float4 pb = *(const float4*)&Pp_sh[k8 * 8 + 4];
            aq[0]=pa.x; aq[1]=pa.y; aq[2]=pa.z; aq[3]=pa.w;
            aq[4]=pb.x; aq[5]=pb.y; aq[6]=pb.z; aq[7]=pb.w;
        }
        float qe = 0.0f;
        #pragma unroll
        for (int j = 0; j < 8; ++j) {
            const float dj  = lane_bcast(aq[j], j);
            qe += __logf(dj);
            const float rv2 = fast_rcp(dj);
            const float tq  = (k8 > j) ? aq[j] * rv2 : 0.0f;
            float u[8];
            #pragma unroll
            for (int i = j + 1; i < 8; ++i) u[i] = lane_bcast(aq[i], j);
            #pragma unroll
            for (int i = j + 1; i < 8; ++i) aq[i] = fmaf(-tq, u[i], aq[i]);
        }
        if (lane == 0) out[qbase + (T_LEN - 1)] = 0.5f * qe;
    }
}

extern "C" void kernel_launch(void* const* d_in, const int* in_sizes, int n_in,
                              void* d_out, int out_size, void* d_ws, size_t ws_size,
                              hipStream_t stream) {
    (void)in_sizes; (void)n_in; (void)out_size; (void)d_ws; (void)ws_size;
    const float* X0 = (const float*)d_in[0];
    const float* U  = (const float*)d_in[1];
    const float* Y  = (const float*)d_in[2];
    const float* W1 = (const float*)d_in[3];
    const float* B1 = (const float*)d_in[4];
    const float* W2 = (const float*)d_in[5];
    const float* B2 = (const float*)d_in[6];
    const float* HM = (const float*)d_in[7];
    const float* LQ = (const float*)d_in[8];
    const float* LR = (const float*)d_in[9];
    const float* LP0 = (const float*)d_in[10];
    float* out = (float*)d_out;
    ukf_kernel<<<dim3(B_LEN), dim3(128), 0, stream>>>(X0, U, Y, W1, B1, W2, B2,
                                                      HM, LQ, LR, LP0, out);
}

// Round 13
// 797.579 us; speedup vs baseline: 3.1827x; 1.0044x over previous
//
#include <hip/hip_runtime.h>
#include <math.h>

#define B_LEN 1024
#define T_LEN 256
#define HST 36   // hid_sh leading stride keeps float4 access conflict-light
#define TS 20    // dxT/ypT row stride (17 used + 3 pad): banks 20*r%32 distinct

__device__ __forceinline__ float fast_rcp(float x) { return __builtin_amdgcn_rcpf(x); }
__device__ __forceinline__ float fast_rsq(float x) { return __builtin_amdgcn_rsqf(x); }
__device__ __forceinline__ float lane_bcast(float v, int l) {
    return __int_as_float(__builtin_amdgcn_readlane(__float_as_int(v), l));
}
__device__ __forceinline__ float fast_tanh(float x) {
    float e = __expf(2.0f * x);
    return 1.0f - 2.0f * fast_rcp(e + 1.0f);
}
__device__ __forceinline__ float softplus_f(float x) {
    return (x > 20.0f) ? x : log1pf(expf(x));
}
// weighted 17-dot: 0.0625*sum(all 17) + (2-0.0625)*center  (Wc0=2, rest 1/16)
__device__ __forceinline__ float wdot17(const float* __restrict__ a,
                                        const float* __restrict__ b) {
    float full = 0.0f;
    #pragma unroll
    for (int c = 0; c < 4; ++c) {
        const float4 av = *(const float4*)&a[c * 4];
        const float4 bv = *(const float4*)&b[c * 4];
        full += av.x * bv.x + av.y * bv.y + av.z * bv.z + av.w * bv.w;
    }
    full += a[16] * b[16];
    return 0.0625f * full + 1.9375f * a[0] * b[0];
}

// FINAL: exact revert to the R8 verified kernel (750us counter-dur) -- the
// best measured configuration. Structure: one batch per 128-thread block
// (2 waves, 8/CU -> 2 waves/SIMD chip-wide), 4 barriers.
// Search record (931.8 -> 750, -20%):
//  WINS: branchless chol8 + qe-LDL; readlane-K; parallel cofactor Sy^-1
//        (single-log r_e); symmetric P_new (kk . Pxy-row); phase-D
//        rebalance (merged Pxy+Sy on w1); symmetric Pp row readbacks.
//  CLOSED directions (all measured): 1 wave/SIMD (R2 977us), in-wave
//        2-batch ILP (R3 2x, zero overlap), 8-wave/128-CU (R4), 4-wave
//        blocks (R10 spill / R11 1388us spill-free), block de-phasing
//        (R9 neutral), deferred qe (R12 neutral -> E not qe-bound).
//  Not memory-bound (HBM 1.3%), not issue-bound (VALU 59% at optimal
//  TLP): floor is dependent-latency of the 255-step sequential scan.
__global__ __launch_bounds__(128, 2)
void ukf_kernel(const float* __restrict__ X0, const float* __restrict__ U,
                const float* __restrict__ Y,  const float* __restrict__ W1,
                const float* __restrict__ B1, const float* __restrict__ W2,
                const float* __restrict__ B2, const float* __restrict__ HM,
                const float* __restrict__ LQ, const float* __restrict__ LR,
                const float* __restrict__ LP0, float* __restrict__ out)
{
    const int tid  = threadIdx.x;
    const int wid  = tid >> 6;
    const int lane = tid & 63;
    const int b    = blockIdx.x;
    const int k8   = lane & 7;        // column / j8
    const int g8   = lane >> 3;       // replica group / i8
    const int i8   = g8;
    const int j8   = k8;
    const int h32  = lane & 31;
    const int p2   = lane >> 5;       // half-wave (L1 row parity)
    const int m4   = lane & 3;
    const int sy   = lane >> 2;

    __shared__ __align__(16) float u_sh[T_LEN * 2];
    __shared__ __align__(16) float y_sh[T_LEN * 4];
    __shared__ __align__(16) float pts_sh[17 * 8];
    __shared__ __align__(16) float hid_sh[17 * HST];
    __shared__ __align__(16) float pf_sh[17 * 8];
    __shared__ __align__(16) float dxT_sh[8 * TS];   // dxT[d][s]
    __shared__ __align__(16) float ypT_sh[4 * TS];   // ypT[m][s]
    __shared__ __align__(16) float xp_sh[8];
    __shared__ __align__(16) float ypred_sh[4];
    __shared__ __align__(16) float Sy_sh[16];
    __shared__ __align__(16) float Si_sh[16];
    __shared__ __align__(16) float Pxy_sh[32];
    __shared__ __align__(16) float Pp_sh[64];

    // ---- one-time staging ----
    for (int k = tid; k < T_LEN * 2; k += 128) u_sh[k] = U[(size_t)b * (T_LEN * 2) + k];
    for (int k = tid; k < T_LEN * 4; k += 128) y_sh[k] = Y[(size_t)b * (T_LEN * 4) + k];

    float w1r[10];
    #pragma unroll
    for (int d = 0; d < 10; ++d) w1r[d] = W1[d * 32 + h32];
    const float b1r = B1[h32];
    float w2r[32];
    #pragma unroll
    for (int h = 0; h < 32; ++h) w2r[h] = W2[h * 8 + k8];
    const float b2r = B2[k8];
    float hmr[8];                              // wave1 only
    #pragma unroll
    for (int d = 0; d < 8; ++d) hmr[d] = HM[m4 * 8 + d];

    const float qdiag = softplus_f(LQ[i8]);    // w0 Ppred
    const float rdiag = softplus_f(LR[m4]);    // w1 Sy

    const size_t Xbase = (size_t)b * T_LEN * 8;
    const size_t Pbase = (size_t)B_LEN * T_LEN * 8  + (size_t)b * T_LEN * 64;
    const size_t qbase = (size_t)B_LEN * T_LEN * 72 + (size_t)b * T_LEN;
    const size_t rbase = (size_t)B_LEN * T_LEN * 73 + (size_t)b * T_LEN;

    // ---- persistent register state (w0): x replicated, P column k8 ----
    float xn[8], Pc[8];
    {
        const float4 xa = *(const float4*)&X0[b * 8];
        const float4 xb = *(const float4*)&X0[b * 8 + 4];
        xn[0] = xa.x; xn[1] = xa.y; xn[2] = xa.z; xn[3] = xa.w;
        xn[4] = xb.x; xn[5] = xb.y; xn[6] = xb.z; xn[7] = xb.w;
        const float p0k = softplus_f(LP0[k8]);
        #pragma unroll
        for (int i = 0; i < 8; ++i) Pc[i] = (i == k8) ? p0k : 0.0f;
    }
    if (wid == 0) {
        out[Pbase + lane] = Pc[g8];                  // coalesced 64-lane P store
        if (lane == 0) {
            *(float4*)&out[Xbase]     = make_float4(xn[0], xn[1], xn[2], xn[3]);
            *(float4*)&out[Xbase + 4] = make_float4(xn[4], xn[5], xn[6], xn[7]);
            out[qbase] = 0.0f; out[rbase] = 0.0f;
        }
    }

    for (int t = 1; t < T_LEN; ++t) {
        // ===== Phase A [w0]: branchless column-chol8 of 8P+jitter -> pts =====
        if (wid == 0) {
            float a[8];
            #pragma unroll
            for (int i = 0; i < 8; ++i) a[i] = 8.0f * Pc[i] + ((i == k8) ? 1e-4f : 0.0f);
            #pragma unroll
            for (int j = 0; j < 8; ++j) {
                const float dj = lane_bcast(a[j], j);
                const float rv = fast_rsq(dj);
                const float sc = (k8 == j) ? rv : 1.0f;
                const float tc = (k8 > j) ? a[j] * (rv * rv) : 0.0f;
                float u[8];
                #pragma unroll
                for (int i = j + 1; i < 8; ++i) u[i] = lane_bcast(a[i], j);
                #pragma unroll
                for (int i = j + 1; i < 8; ++i) a[i] = sc * a[i] - tc * u[i];
                a[j] = (k8 == j) ? dj * rv : a[j];
            }
            float Lc[8];
            #pragma unroll
            for (int i = 0; i < 8; ++i) Lc[i] = (i >= k8) ? a[i] : 0.0f;
            if (g8 == 0) {
                *(float4*)&pts_sh[(1 + k8) * 8] =
                    make_float4(xn[0] + Lc[0], xn[1] + Lc[1], xn[2] + Lc[2], xn[3] + Lc[3]);
                *(float4*)&pts_sh[(1 + k8) * 8 + 4] =
                    make_float4(xn[4] + Lc[4], xn[5] + Lc[5], xn[6] + Lc[6], xn[7] + Lc[7]);
            } else if (g8 == 1) {
                *(float4*)&pts_sh[(9 + k8) * 8] =
                    make_float4(xn[0] - Lc[0], xn[1] - Lc[1], xn[2] - Lc[2], xn[3] - Lc[3]);
                *(float4*)&pts_sh[(9 + k8) * 8 + 4] =
                    make_float4(xn[4] - Lc[4], xn[5] - Lc[5], xn[6] - Lc[6], xn[7] - Lc[7]);
            } else if (g8 == 2 && k8 == 0) {
                *(float4*)&pts_sh[0] = make_float4(xn[0], xn[1], xn[2], xn[3]);
                *(float4*)&pts_sh[4] = make_float4(xn[4], xn[5], xn[6], xn[7]);
            }
        }
        __syncthreads();   // b1: pts ready

        // ===== Phase B [both]: fused L1+L2, per-wave sigma sets ===============
        {
            const float u0 = u_sh[(t - 1) * 2 + 0];
            const float u1 = u_sh[(t - 1) * 2 + 1];
            const float ub = b1r + u0 * w1r[8] + u1 * w1r[9];
            if (wid == 0) {
                #pragma unroll
                for (int p = 0; p < 4; ++p) {
                    const int s = 2 * p + p2;                 // rows 0..7
                    const float4 pa = *(const float4*)&pts_sh[s * 8];
                    const float4 pb = *(const float4*)&pts_sh[s * 8 + 4];
                    float acc = ub
                        + pa.x * w1r[0] + pa.y * w1r[1] + pa.z * w1r[2] + pa.w * w1r[3]
                        + pb.x * w1r[4] + pb.y * w1r[5] + pb.z * w1r[6] + pb.w * w1r[7];
                    hid_sh[s * HST + h32] = fast_tanh(acc);
                }
            } else {
                #pragma unroll
                for (int p = 0; p < 4; ++p) {
                    const int s = 8 + 2 * p + p2;             // rows 8..15
                    const float4 pa = *(const float4*)&pts_sh[s * 8];
                    const float4 pb = *(const float4*)&pts_sh[s * 8 + 4];
                    float acc = ub
                        + pa.x * w1r[0] + pa.y * w1r[1] + pa.z * w1r[2] + pa.w * w1r[3]
                        + pb.x * w1r[4] + pb.y * w1r[5] + pb.z * w1r[6] + pb.w * w1r[7];
                    hid_sh[s * HST + h32] = fast_tanh(acc);
                }
                if (p2 == 0) {                                // row 16
                    const float4 pa = *(const float4*)&pts_sh[16 * 8];
                    const float4 pb = *(const float4*)&pts_sh[16 * 8 + 4];
                    float acc = ub
                        + pa.x * w1r[0] + pa.y * w1r[1] + pa.z * w1r[2] + pa.w * w1r[3]
                        + pb.x * w1r[4] + pb.y * w1r[5] + pb.z * w1r[6] + pb.w * w1r[7];
                    hid_sh[16 * HST + h32] = fast_tanh(acc);
                }
            }
            // L2 on own-wave rows (same-wave DS in-order: no barrier)
            const int srow = (wid == 0) ? g8 : (8 + g8);
            float acc = b2r;
            #pragma unroll
            for (int h = 0; h < 32; h += 4) {
                const float4 hv = *(const float4*)&hid_sh[srow * HST + h];
                acc += hv.x * w2r[h] + hv.y * w2r[h + 1] + hv.z * w2r[h + 2] + hv.w * w2r[h + 3];
            }
            pf_sh[srow * 8 + k8] = pts_sh[srow * 8 + k8] + acc;
            if (wid == 1 && lane < 8) {
                float a16 = b2r;
                #pragma unroll
                for (int h = 0; h < 32; h += 4) {
                    const float4 hv = *(const float4*)&hid_sh[16 * HST + h];
                    a16 += hv.x * w2r[h] + hv.y * w2r[h + 1] + hv.z * w2r[h + 2] + hv.w * w2r[h + 3];
                }
                pf_sh[16 * 8 + lane] = pts_sh[16 * 8 + lane] + a16;
            }
        }
        __syncthreads();   // b2: pf ready

        // ===== Phase C [w0]: x_pred + dxT ; [w1]: y_pts + ypred + ypT =========
        if (wid == 0) {
            const float v0   = pf_sh[i8 * 8 + j8];
            const float v1   = pf_sh[(8 + i8) * 8 + j8];
            const float pf16 = (i8 == 0) ? pf_sh[16 * 8 + j8] : 0.0f;
            float part = ((i8 == 0) ? pf16 : v0) + v1;        // s=16 replaces s=0
            part += __shfl_xor(part, 8);
            part += __shfl_xor(part, 16);
            part += __shfl_xor(part, 32);
            const float xp = part * 0.0625f;
            if (i8 == 0) xp_sh[j8] = xp;
            dxT_sh[j8 * TS + i8]       = v0 - xp;             // dxT[d][s]
            dxT_sh[j8 * TS + 8 + i8]   = v1 - xp;
            if (i8 == 0) dxT_sh[j8 * TS + 16] = pf16 - xp;
        } else {
            float yv0, yv16 = 0.0f;
            {
                const float4 pa = *(const float4*)&pf_sh[sy * 8];
                const float4 pb = *(const float4*)&pf_sh[sy * 8 + 4];
                yv0 = pa.x * hmr[0] + pa.y * hmr[1] + pa.z * hmr[2] + pa.w * hmr[3]
                    + pb.x * hmr[4] + pb.y * hmr[5] + pb.z * hmr[6] + pb.w * hmr[7];
            }
            if (sy == 0) {
                const float4 pa = *(const float4*)&pf_sh[16 * 8];
                const float4 pb = *(const float4*)&pf_sh[16 * 8 + 4];
                yv16 = pa.x * hmr[0] + pa.y * hmr[1] + pa.z * hmr[2] + pa.w * hmr[3]
                     + pb.x * hmr[4] + pb.y * hmr[5] + pb.z * hmr[6] + pb.w * hmr[7];
            }
            float py = (sy == 0) ? yv16 : yv0;
            py += __shfl_xor(py, 4);
            py += __shfl_xor(py, 8);
            py += __shfl_xor(py, 16);
            py += __shfl_xor(py, 32);
            const float ypred = py * 0.0625f;
            if (lane < 4) ypred_sh[lane] = ypred;
            ypT_sh[m4 * TS + sy] = yv0 - ypred;               // ypT[m][s]
            if (sy == 0) ypT_sh[m4 * TS + 16] = yv16 - ypred;
        }
        __syncthreads();   // b3: dxT, ypT, xp, ypred ready

        // ===== Phase D: [w0] Ppred only ; [w1] merged Pxy+Sy -> cofactor Si ===
        float Ppc[8];
        if (wid == 0) {
            const float Ppred = wdot17(&dxT_sh[i8 * TS], &dxT_sh[j8 * TS])
                              + ((i8 == j8) ? (qdiag + 1e-4f) : 0.0f);
            Pp_sh[lane] = Ppred;
            // Pp exactly symmetric -> column k8 == row k8 (contiguous):
            // 2x ds_read_b128, 2-way bank alias (free), in-wave ordering.
            const float4 pa = *(const float4*)&Pp_sh[k8 * 8];
            const float4 pb = *(const float4*)&Pp_sh[k8 * 8 + 4];
            Ppc[0]=pa.x; Ppc[1]=pa.y; Ppc[2]=pa.z; Ppc[3]=pa.w;
            Ppc[4]=pb.x; Ppc[5]=pb.y; Ppc[6]=pb.z; Ppc[7]=pb.w;
        } else {
            // merged round (R2-verified): lanes<32 -> Pxy(ii=sy, mm=m4);
            // lanes 32..47 -> Sy(r2, m4). dxT read fenced by b3.
            const int r2 = (lane < 32) ? sy : (sy & 3);
            const float* pa2 = (lane < 32) ? &dxT_sh[r2 * TS] : &ypT_sh[r2 * TS];
            float v2 = wdot17(pa2, &ypT_sh[m4 * TS]);
            v2 += ((lane >= 32) && (r2 == m4)) ? rdiag : 0.0f;
            if (lane < 32)      Pxy_sh[lane] = v2;
            else if (lane < 48) Sy_sh[r2 * 4 + m4] = v2;
            // parallel cofactor inverse (R7-verified); Sy_sh read in-wave
            float cof;
            {
                const int i4 = sy & 3;
                const int j4 = m4;
                const int r0 = (i4 == 0) ? 1 : 0;
                const int r1 = (i4 <= 1) ? 2 : 1;
                const int rr = (i4 <= 2) ? 3 : 2;
                const int c0 = (j4 == 0) ? 1 : 0;
                const int c1 = (j4 <= 1) ? 2 : 1;
                const int cc = (j4 <= 2) ? 3 : 2;
                const float m00 = Sy_sh[r0 * 4 + c0], m01 = Sy_sh[r0 * 4 + c1], m02 = Sy_sh[r0 * 4 + cc];
                const float m10 = Sy_sh[r1 * 4 + c0], m11 = Sy_sh[r1 * 4 + c1], m12 = Sy_sh[r1 * 4 + cc];
                const float m20 = Sy_sh[rr * 4 + c0], m21 = Sy_sh[rr * 4 + c1], m22 = Sy_sh[rr * 4 + cc];
                const float d3 = m00 * (m11 * m22 - m12 * m21)
                               - m01 * (m10 * m22 - m12 * m20)
                               + m02 * (m10 * m21 - m11 * m20);
                cof = (((i4 + j4) & 1) ? -d3 : d3);
            }
            const float c0b = lane_bcast(cof, 0);
            const float c1b = lane_bcast(cof, 1);
            const float c2b = lane_bcast(cof, 2);
            const float c3b = lane_bcast(cof, 3);
            const float4 sy0 = *(const float4*)&Sy_sh[0];
            const float det = sy0.x * c0b + sy0.y * c1b + sy0.z * c2b + sy0.w * c3b;
            if (lane == 0) out[rbase + t] = 0.5f * __logf(det);
            const float rdet = fast_rcp(det);
            if (lane < 16) Si_sh[lane] = cof * rdet;
        }
        __syncthreads();   // b4: Pp / Si / Pxy ready

        // ===== Phase E: [w0] kk -> P_new(symmetric form), x_new ; [w1] qe =====
        if (wid == 0) {
            float Si[16];
            {
                const float4 a0 = *(const float4*)&Si_sh[0];
                const float4 a1 = *(const float4*)&Si_sh[4];
                const float4 a2 = *(const float4*)&Si_sh[8];
                const float4 a3 = *(const float4*)&Si_sh[12];
                Si[0]=a0.x;  Si[1]=a0.y;  Si[2]=a0.z;  Si[3]=a0.w;
                Si[4]=a1.x;  Si[5]=a1.y;  Si[6]=a1.z;  Si[7]=a1.w;
                Si[8]=a2.x;  Si[9]=a2.y;  Si[10]=a2.z; Si[11]=a2.w;
                Si[12]=a3.x; Si[13]=a3.y; Si[14]=a3.z; Si[15]=a3.w;
            }
            const float4 pr = *(const float4*)&Pxy_sh[k8 * 4];     // Pxy row k8
            float kk[4];
            #pragma unroll
            for (int aa = 0; aa < 4; ++aa)
                kk[aa] = pr.x * Si[0 * 4 + aa] + pr.y * Si[1 * 4 + aa]
                       + pr.z * Si[2 * 4 + aa] + pr.w * Si[3 * 4 + aa];
            // all 8 Pxy rows (broadcast LDS reads, compile-time indexed regs)
            float Pr[32];
            {
                const float4 q0 = *(const float4*)&Pxy_sh[0];
                const float4 q1 = *(const float4*)&Pxy_sh[4];
                const float4 q2 = *(const float4*)&Pxy_sh[8];
                const float4 q3 = *(const float4*)&Pxy_sh[12];
                const float4 q4 = *(const float4*)&Pxy_sh[16];
                const float4 q5 = *(const float4*)&Pxy_sh[20];
                const float4 q6 = *(const float4*)&Pxy_sh[24];
                const float4 q7 = *(const float4*)&Pxy_sh[28];
                Pr[0]=q0.x;  Pr[1]=q0.y;  Pr[2]=q0.z;  Pr[3]=q0.w;
                Pr[4]=q1.x;  Pr[5]=q1.y;  Pr[6]=q1.z;  Pr[7]=q1.w;
                Pr[8]=q2.x;  Pr[9]=q2.y;  Pr[10]=q2.z; Pr[11]=q2.w;
                Pr[12]=q3.x; Pr[13]=q3.y; Pr[14]=q3.z; Pr[15]=q3.w;
                Pr[16]=q4.x; Pr[17]=q4.y; Pr[18]=q4.z; Pr[19]=q4.w;
                Pr[20]=q5.x; Pr[21]=q5.y; Pr[22]=q5.z; Pr[23]=q5.w;
                Pr[24]=q6.x; Pr[25]=q6.y; Pr[26]=q6.z; Pr[27]=q6.w;
                Pr[28]=q7.x; Pr[29]=q7.y; Pr[30]=q7.z; Pr[31]=q7.w;
            }
            // P_new column k8: Pc[i] = Ppc[i] - dot(kk, Pxy row i)  (+ jitter)
            #pragma unroll
            for (int i = 0; i < 8; ++i) {
                const float m = kk[0] * Pr[i * 4 + 0] + kk[1] * Pr[i * 4 + 1]
                              + kk[2] * Pr[i * 4 + 2] + kk[3] * Pr[i * 4 + 3];
                Pc[i] = Ppc[i] - m + ((i == k8) ? 1e-4f : 0.0f);
            }
            // x_new: own row k8 then broadcast (lane r<8 has k8==r)
            const float4 yt = *(const float4*)&y_sh[t * 4];
            const float4 yp = *(const float4*)&ypred_sh[0];
            const float in0 = yt.x - yp.x, in1 = yt.y - yp.y;
            const float in2 = yt.z - yp.z, in3 = yt.w - yp.w;
            const float xo = xp_sh[k8]
                           + kk[0] * in0 + kk[1] * in1 + kk[2] * in2 + kk[3] * in3;
            #pragma unroll
            for (int i = 0; i < 8; ++i) xn[i] = lane_bcast(xo, i);
            // stores: coalesced 64-lane P store (lane (g8,k8) owns P[g8][k8])
            out[Pbase + (size_t)t * 64 + lane] = Pc[g8];
            if (lane == 0) {
                *(float4*)&out[Xbase + (size_t)t * 8]     = make_float4(xn[0], xn[1], xn[2], xn[3]);
                *(float4*)&out[Xbase + (size_t)t * 8 + 4] = make_float4(xn[4], xn[5], xn[6], xn[7]);
            }
        } else {
            // qe = 0.5 slogdet(P_pred): branchless column LDL; aq = Pp row k8
            float aq[8];
            {
                const float4 pa = *(const float4*)&Pp_sh[k8 * 8];
                const float4 pb = *(const float4*)&Pp_sh[k8 * 8 + 4];
                aq[0]=pa.x; aq[1]=pa.y; aq[2]=pa.z; aq[3]=pa.w;
                aq[4]=pb.x; aq[5]=pb.y; aq[6]=pb.z; aq[7]=pb.w;
            }
            float qe = 0.0f;
            #pragma unroll
            for (int j = 0; j < 8; ++j) {
                const float dj  = lane_bcast(aq[j], j);
                qe += __logf(dj);
                const float rv2 = fast_rcp(dj);
                const float tq  = (k8 > j) ? aq[j] * rv2 : 0.0f;
                float u[8];
                #pragma unroll
                for (int i = j + 1; i < 8; ++i) u[i] = lane_bcast(aq[i], j);
                #pragma unroll
                for (int i = j + 1; i < 8; ++i) aq[i] = fmaf(-tq, u[i], aq[i]);
            }
            if (lane == 0) out[qbase + t] = 0.5f * qe;
        }
        // no trailing barrier: next-step hazards are covered by b1..b4 ordering
    }
}

extern "C" void kernel_launch(void* const* d_in, const int* in_sizes, int n_in,
                              void* d_out, int out_size, void* d_ws, size_t ws_size,
                              hipStream_t stream) {
    (void)in_sizes; (void)n_in; (void)out_size; (void)d_ws; (void)ws_size;
    const float* X0 = (const float*)d_in[0];
    const float* U  = (const float*)d_in[1];
    const float* Y  = (const float*)d_in[2];
    const float* W1 = (const float*)d_in[3];
    const float* B1 = (const float*)d_in[4];
    const float* W2 = (const float*)d_in[5];
    const float* B2 = (const float*)d_in[6];
    const float* HM = (const float*)d_in[7];
    const float* LQ = (const float*)d_in[8];
    const float* LR = (const float*)d_in[9];
    const float* LP0 = (const float*)d_in[10];
    float* out = (float*)d_out;
    ukf_kernel<<<dim3(B_LEN), dim3(128), 0, stream>>>(X0, U, Y, W1, B1, W2, B2,
                                                      HM, LQ, LR, LP0, out);
}